// Round 8
// baseline (263.036 us; speedup 1.0000x reference)
//
#include <hip/hip_runtime.h>
#include <stdint.h>

#define M_DIM 4096
#define T_DIM 2048
#define N_OUT 2024
#define N_PAD 2048
#define WIN   25
#define K_DIM 4096

typedef float f32x4 __attribute__((ext_vector_type(4)));

__device__ __forceinline__ unsigned short f2bf(float x) {
  unsigned u = __float_as_uint(x);
  u += 0x7FFF + ((u >> 16) & 1);           // round-to-nearest-even
  return (unsigned short)(u >> 16);
}
__device__ __forceinline__ float bf2f(unsigned short h) {
  return __uint_as_float(((unsigned)h) << 16);
}

__device__ __forceinline__ void gl2lds16(const void* g, void* l) {
  // 16B-wide async global->LDS; HW dest = wave-uniform base + lane*16
  __builtin_amdgcn_global_load_lds(
      (const __attribute__((address_space(1))) unsigned int*)g,
      (__attribute__((address_space(3))) unsigned int*)l, 16, 0, 0);
}

// pack 4 floats -> 4 e4m3 bytes (one dword)
__device__ __forceinline__ int pk_fp8x4(float a, float b, float c, float d) {
  int w = __builtin_amdgcn_cvt_pk_fp8_f32(a, b, 0, false);
  w = __builtin_amdgcn_cvt_pk_fp8_f32(c, d, w, true);
  return w;
}

// ---------- Kernel 1: W8 = e4m3(sigmoid(alphas)), diagonal -> 0 ----------
__global__ __launch_bounds__(256) void k_wcast(const float* __restrict__ alphas,
                                               unsigned char* __restrict__ W8) {
  size_t i8 = ((size_t)blockIdx.x * 256 + threadIdx.x) * 8;
  const float4 v0 = *(const float4*)(alphas + i8);
  const float4 v1 = *(const float4*)(alphas + i8 + 4);
  int row = (int)(i8 >> 12);
  int col = (int)(i8 & 4095);
  float a[8] = {v0.x, v0.y, v0.z, v0.w, v1.x, v1.y, v1.z, v1.w};
  float w[8];
#pragma unroll
  for (int j = 0; j < 8; ++j)
    w[j] = (row == col + j) ? 0.f : 1.f / (1.f + __expf(-a[j]));
  int p0 = pk_fp8x4(w[0], w[1], w[2], w[3]);
  int p1 = pk_fp8x4(w[4], w[5], w[6], w[7]);
  *(uint2*)(W8 + i8) = uint2{(unsigned)p0, (unsigned)p1};
}

// ---------- Kernel 2: merged conv + transpose (ys read ONCE) ----------
// R13 version verbatim (passed).
__global__ __launch_bounds__(256) void k_convT(const float* __restrict__ ys,
                                               const float* __restrict__ repro,
                                               unsigned short* __restrict__ Sbf,
                                               unsigned char* __restrict__ BT8) {
  __shared__ float sy[32][284];   // 280 used + pad
  __shared__ float sr[32][26];
  const int tid = threadIdx.x;
  const int c0 = blockIdx.x * 256;   // 0..7 -> col chunk
  const int m0 = blockIdx.y * 32;    // 0..127 -> row chunk

  for (int slot = tid; slot < 32 * 70; slot += 256) {
    int r = slot / 70, f = slot % 70;
    int c = c0 + f * 4;
    float4 v = (c < T_DIM) ? *(const float4*)(ys + (size_t)(m0 + r) * T_DIM + c)
                           : float4{0.f, 0.f, 0.f, 0.f};
    sy[r][f * 4 + 0] = v.x; sy[r][f * 4 + 1] = v.y;
    sy[r][f * 4 + 2] = v.z; sy[r][f * 4 + 3] = v.w;
  }
  for (int slot = tid; slot < 32 * WIN; slot += 256) {
    int r = slot / WIN, k = slot % WIN;
    sr[r][k] = repro[(m0 + r) * WIN + k];
  }
  __syncthreads();

  // ---- conv ----
  {
    const int r = tid >> 3;
    const int cbase = (tid & 7) * 32;
    float y[56];
#pragma unroll
    for (int i = 0; i < 56; ++i) y[i] = sy[r][cbase + i];
    float rv[WIN];
#pragma unroll
    for (int k = 0; k < WIN; ++k) rv[k] = sr[r][k];
    unsigned pk[16];
#pragma unroll
    for (int jj = 0; jj < 32; ++jj) {
      float z = 0.f;
#pragma unroll
      for (int k = 0; k < WIN; ++k) z += y[jj + k] * rv[k];   // same k-order as R0
      float sp = fmaxf(z, 0.f) + log1pf(__expf(-fabsf(z)));
      int gj = c0 + cbase + jj;
      unsigned short h = (gj < N_OUT) ? f2bf(sp) : (unsigned short)0;
      if (jj & 1) pk[jj >> 1] |= ((unsigned)h) << 16;
      else        pk[jj >> 1]  = (unsigned)h;
    }
    unsigned short* dst = Sbf + (size_t)(m0 + r) * N_PAD + c0 + cbase;
    *(uint4*)(dst)      = *(const uint4*)(pk + 0);
    *(uint4*)(dst + 8)  = *(const uint4*)(pk + 4);
    *(uint4*)(dst + 16) = *(const uint4*)(pk + 8);
    *(uint4*)(dst + 24) = *(const uint4*)(pk + 12);
  }

  // ---- BT8 ----
  {
    const int n = c0 + tid;
    const bool ok = (n < N_OUT);
    unsigned w[8];
#pragma unroll
    for (int i = 0; i < 8; ++i) {
      float a0 = ok ? sy[4 * i + 0][tid + 24] : 0.f;
      float a1 = ok ? sy[4 * i + 1][tid + 24] : 0.f;
      float a2 = ok ? sy[4 * i + 2][tid + 24] : 0.f;
      float a3 = ok ? sy[4 * i + 3][tid + 24] : 0.f;
      w[i] = (unsigned)pk_fp8x4(a0, a1, a2, a3);
    }
    unsigned char* dst = BT8 + (size_t)n * K_DIM + m0;
    *(uint4*)(dst)      = uint4{w[0], w[1], w[2], w[3]};
    *(uint4*)(dst + 16) = uint4{w[4], w[5], w[6], w[7]};
  }
}

// ---------- GEMM: C = W8 @ BT8^T (fp8 MFMA), out = beta * (S + C) ----------
// R15 = R14 with the one risky construct fixed: global_load_lds LDS base
// is now EXPLICITLY wave-uniform (&lds[wave*1024]; HW adds lane*16). R14
// passed a per-lane pointer (tid*16) relying on implicit readfirstlane —
// the only deviation from every passing round, and the prime suspect if
// the container death was kernel-side.
// Structure: 256x128 tile cuts staged bytes 25% (512->384 MB). 1024
// threads, 16 waves (4M x 4N), wave = 64x32 out (R9's proven fragment
// math + epilogue + XOR chunk swizzle). Ping-pong depth-2, counted vmcnt
// with per-wave roles: waves 0-7 stage A+B (vmcnt(2)), waves 8-15 stage
// A only (vmcnt(1)). LDS 48 KB. Accumulation chain unchanged -> identical
// numerics.
__global__ __launch_bounds__(1024, 4) void k_gemm(const unsigned char* __restrict__ W8,
                                                  const unsigned char* __restrict__ BT8,
                                                  const unsigned short* __restrict__ Sbf,
                                                  const float* __restrict__ b0,
                                                  const float* __restrict__ b1,
                                                  float* __restrict__ out) {
  __shared__ __align__(64) unsigned char lA[2][256 * 64];   // 32 KB
  __shared__ __align__(64) unsigned char lB[2][128 * 64];   // 16 KB
  const int tid  = threadIdx.x;
  const int wave = tid >> 6;          // 0..15
  const int lane = tid & 63;
  const int wm = wave >> 2;           // 0..3 : 64-row slice of 256
  const int wn = wave & 3;            // 0..3 : 32-col slice of 128
  const int m16  = lane & 15;
  const int quad = lane >> 4;

  // XCD-aware bijective swizzle (256 blocks, 256%8==0): 32 tiles/XCD,
  // consecutive in M -> A-panels L2-local.
  const int fid  = blockIdx.y * gridDim.x + blockIdx.x;   // 0..255
  const int swz  = (fid & 7) * 32 + (fid >> 3);
  const int tileN = (swz & 15) * 128;
  const int tileM = (swz >> 4) * 256;

  // fragment read offsets: 64B rows (K=64 fp8 per kstep).
  // MFMA h (k-half, K=32): lane reads bytes k = h*32 + quad*8 .. +7
  // chunk c = 2h + (quad>>1); swizzled slot = c ^ ((row>>1)&3);
  // row bits 1-2 == m16 bits 1-2 for all fragment rows.
  const int key  = (m16 >> 1) & 3;
  const int sub  = (quad & 1) * 8;
  const int rowA = (wm * 64 + m16) * 64;
  const int rowB = (wn * 32 + m16) * 64;
  int hOf[2];
#pragma unroll
  for (int h = 0; h < 2; ++h)
    hOf[h] = (((2 * h + (quad >> 1)) ^ key) << 4) + sub;

  // A staging: all 1024 threads, 16 B each (16 KB/kstep); thread covers
  // byte range tid*16..+15 -> row rA = tid/4, chunk slot (tid&3).
  const int oA = tid * 16;            // 0..16383
  const int rA = oA >> 6;             // row 0..255
  const int sA = (oA >> 4) & 3;
  const int qA = sA ^ ((rA >> 1) & 3);
  const unsigned char* gA = W8 + (size_t)(tileM + rA) * K_DIM + qA * 16;
  // B staging: waves 0-7 (tid<512), 16 B each (8 KB/kstep).
  const int rB = (tid * 16) >> 6;     // row 0..127 for tid<512
  const int qB = (((tid * 16) >> 4) & 3) ^ ((rB >> 1) & 3);
  const unsigned char* gB = BT8 + (size_t)(tileN + rB) * K_DIM + qB * 16;
  // EXPLICIT wave-uniform LDS bases (HW adds lane*16):
  const int ldsBase = wave * 1024;

  f32x4 acc[4][2];
#pragma unroll
  for (int i = 0; i < 4; ++i)
#pragma unroll
    for (int j = 0; j < 2; ++j) acc[i][j] = f32x4{0.f, 0.f, 0.f, 0.f};

  auto stage = [&](int buf, int kt_) {
    const size_t kb_ = (size_t)kt_ * 64;
    gl2lds16(gA + kb_, &lA[buf][ldsBase]);
    if (wave < 8) gl2lds16(gB + kb_, &lB[buf][ldsBase]);
  };
  auto compute = [&](int buf) {
#pragma unroll
    for (int h = 0; h < 2; ++h) {
      long long aF[4], bF[2];
#pragma unroll
      for (int i = 0; i < 4; ++i)
        aF[i] = *(const long long*)&lA[buf][rowA + i * 1024 + hOf[h]];
#pragma unroll
      for (int j = 0; j < 2; ++j)
        bF[j] = *(const long long*)&lB[buf][rowB + j * 1024 + hOf[h]];
#pragma unroll
      for (int i = 0; i < 4; ++i)
#pragma unroll
        for (int j = 0; j < 2; ++j)
          acc[i][j] = __builtin_amdgcn_mfma_f32_16x16x32_fp8_fp8(
              aF[i], bF[j], acc[i][j], 0, 0, 0);
    }
  };

  // prologue: tile 0 in flight
  stage(0, 0);

#pragma unroll 1
  for (int kt = 0; kt < K_DIM / 64; kt += 2) {
    // even phase: prefetch kt+1 -> buf1, wait tile kt, compute buf0
    stage(1, kt + 1);                            // kt <= 62 -> kt+1 valid
    if (wave < 8) {
      asm volatile("s_waitcnt vmcnt(2)" ::: "memory");
    } else {
      asm volatile("s_waitcnt vmcnt(1)" ::: "memory");
    }
    __builtin_amdgcn_s_barrier();
    asm volatile("" ::: "memory");
    compute(0);
    __builtin_amdgcn_s_barrier();
    asm volatile("" ::: "memory");

    // odd phase: prefetch kt+2 -> buf0, wait tile kt+1, compute buf1
    if (kt + 2 < K_DIM / 64) {
      stage(0, kt + 2);
      if (wave < 8) {
        asm volatile("s_waitcnt vmcnt(2)" ::: "memory");
      } else {
        asm volatile("s_waitcnt vmcnt(1)" ::: "memory");
      }
    } else {
      asm volatile("s_waitcnt vmcnt(0)" ::: "memory");
    }
    __builtin_amdgcn_s_barrier();
    asm volatile("" ::: "memory");
    compute(1);
    __builtin_amdgcn_s_barrier();
    asm volatile("" ::: "memory");
  }

  // Epilogue: out[gm][gn] = softplus(b0+b1*(gn+25)) * (S[gm][gn] + C)
#pragma unroll
  for (int j = 0; j < 2; ++j) {
    int gn = tileN + wn * 32 + j * 16 + m16;
    if (gn >= N_OUT) continue;
    float tval = (float)(gn + WIN);
#pragma unroll
    for (int i = 0; i < 4; ++i) {
#pragma unroll
      for (int r2 = 0; r2 < 4; ++r2) {
        int gm = tileM + wm * 64 + i * 16 + quad * 4 + r2;
        float x = b0[gm] + b1[gm] * tval;
        float beta = fmaxf(x, 0.f) + log1pf(__expf(-fabsf(x)));
        float sv = bf2f(Sbf[(size_t)gm * N_PAD + gn]);
        out[(size_t)gm * N_OUT + gn] = beta * (sv + acc[i][j][r2]);
      }
    }
  }
}

extern "C" void kernel_launch(void* const* d_in, const int* in_sizes, int n_in,
                              void* d_out, int out_size, void* d_ws, size_t ws_size,
                              hipStream_t stream) {
  const float* ys     = (const float*)d_in[0];
  const float* alphas = (const float*)d_in[1];
  const float* repro  = (const float*)d_in[2];
  const float* b0     = (const float*)d_in[3];
  const float* b1     = (const float*)d_in[4];
  float* out = (float*)d_out;

  char* ws = (char*)d_ws;
  unsigned char*  W8  = (unsigned char*)ws;                                    // 16 MiB
  unsigned char*  BT8 = (unsigned char*)(ws + (size_t)M_DIM * K_DIM);          //  8 MiB
  unsigned short* Sbf = (unsigned short*)(ws + (size_t)M_DIM * K_DIM
                                             + (size_t)N_PAD * K_DIM);         // 16 MiB

  k_wcast<<<(M_DIM * (size_t)K_DIM) / 8 / 256, 256, 0, stream>>>(alphas, W8);
  k_convT<<<dim3(T_DIM / 256, M_DIM / 32), 256, 0, stream>>>(ys, repro, Sbf, BT8);
  k_gemm<<<dim3(N_PAD / 128, M_DIM / 256), 1024, 0, stream>>>(W8, BT8, Sbf,
                                                              b0, b1, out);
}

// Round 9
// 248.855 us; speedup vs baseline: 1.0570x; 1.0570x over previous
//
#include <hip/hip_runtime.h>
#include <stdint.h>

#define M_DIM 4096
#define T_DIM 2048
#define N_OUT 2024
#define N_PAD 2048
#define WIN   25
#define K_DIM 4096

typedef float f32x4 __attribute__((ext_vector_type(4)));

__device__ __forceinline__ unsigned short f2bf(float x) {
  unsigned u = __float_as_uint(x);
  u += 0x7FFF + ((u >> 16) & 1);           // round-to-nearest-even
  return (unsigned short)(u >> 16);
}
__device__ __forceinline__ float bf2f(unsigned short h) {
  return __uint_as_float(((unsigned)h) << 16);
}

__device__ __forceinline__ void gl2lds16(const void* g, void* l) {
  // 16B-wide async global->LDS; HW dest = wave-uniform base + lane*16
  __builtin_amdgcn_global_load_lds(
      (const __attribute__((address_space(1))) unsigned int*)g,
      (__attribute__((address_space(3))) unsigned int*)l, 16, 0, 0);
}

// pack 4 floats -> 4 e4m3 bytes (one dword)
__device__ __forceinline__ int pk_fp8x4(float a, float b, float c, float d) {
  int w = __builtin_amdgcn_cvt_pk_fp8_f32(a, b, 0, false);
  w = __builtin_amdgcn_cvt_pk_fp8_f32(c, d, w, true);
  return w;
}

// ---------- Kernel 1: W8 = e4m3(sigmoid(alphas)), diagonal -> 0 ----------
__global__ __launch_bounds__(256) void k_wcast(const float* __restrict__ alphas,
                                               unsigned char* __restrict__ W8) {
  size_t i8 = ((size_t)blockIdx.x * 256 + threadIdx.x) * 8;
  const float4 v0 = *(const float4*)(alphas + i8);
  const float4 v1 = *(const float4*)(alphas + i8 + 4);
  int row = (int)(i8 >> 12);
  int col = (int)(i8 & 4095);
  float a[8] = {v0.x, v0.y, v0.z, v0.w, v1.x, v1.y, v1.z, v1.w};
  float w[8];
#pragma unroll
  for (int j = 0; j < 8; ++j)
    w[j] = (row == col + j) ? 0.f : 1.f / (1.f + __expf(-a[j]));
  int p0 = pk_fp8x4(w[0], w[1], w[2], w[3]);
  int p1 = pk_fp8x4(w[4], w[5], w[6], w[7]);
  *(uint2*)(W8 + i8) = uint2{(unsigned)p0, (unsigned)p1};
}

// ---------- Kernel 2: merged conv + transpose (ys read ONCE) ----------
// R13 version verbatim (passed twice).
__global__ __launch_bounds__(256) void k_convT(const float* __restrict__ ys,
                                               const float* __restrict__ repro,
                                               unsigned short* __restrict__ Sbf,
                                               unsigned char* __restrict__ BT8) {
  __shared__ float sy[32][284];   // 280 used + pad
  __shared__ float sr[32][26];
  const int tid = threadIdx.x;
  const int c0 = blockIdx.x * 256;   // 0..7 -> col chunk
  const int m0 = blockIdx.y * 32;    // 0..127 -> row chunk

  for (int slot = tid; slot < 32 * 70; slot += 256) {
    int r = slot / 70, f = slot % 70;
    int c = c0 + f * 4;
    float4 v = (c < T_DIM) ? *(const float4*)(ys + (size_t)(m0 + r) * T_DIM + c)
                           : float4{0.f, 0.f, 0.f, 0.f};
    sy[r][f * 4 + 0] = v.x; sy[r][f * 4 + 1] = v.y;
    sy[r][f * 4 + 2] = v.z; sy[r][f * 4 + 3] = v.w;
  }
  for (int slot = tid; slot < 32 * WIN; slot += 256) {
    int r = slot / WIN, k = slot % WIN;
    sr[r][k] = repro[(m0 + r) * WIN + k];
  }
  __syncthreads();

  // ---- conv ----
  {
    const int r = tid >> 3;
    const int cbase = (tid & 7) * 32;
    float y[56];
#pragma unroll
    for (int i = 0; i < 56; ++i) y[i] = sy[r][cbase + i];
    float rv[WIN];
#pragma unroll
    for (int k = 0; k < WIN; ++k) rv[k] = sr[r][k];
    unsigned pk[16];
#pragma unroll
    for (int jj = 0; jj < 32; ++jj) {
      float z = 0.f;
#pragma unroll
      for (int k = 0; k < WIN; ++k) z += y[jj + k] * rv[k];   // same k-order as R0
      float sp = fmaxf(z, 0.f) + log1pf(__expf(-fabsf(z)));
      int gj = c0 + cbase + jj;
      unsigned short h = (gj < N_OUT) ? f2bf(sp) : (unsigned short)0;
      if (jj & 1) pk[jj >> 1] |= ((unsigned)h) << 16;
      else        pk[jj >> 1]  = (unsigned)h;
    }
    unsigned short* dst = Sbf + (size_t)(m0 + r) * N_PAD + c0 + cbase;
    *(uint4*)(dst)      = *(const uint4*)(pk + 0);
    *(uint4*)(dst + 8)  = *(const uint4*)(pk + 4);
    *(uint4*)(dst + 16) = *(const uint4*)(pk + 8);
    *(uint4*)(dst + 24) = *(const uint4*)(pk + 12);
  }

  // ---- BT8 ----
  {
    const int n = c0 + tid;
    const bool ok = (n < N_OUT);
    unsigned w[8];
#pragma unroll
    for (int i = 0; i < 8; ++i) {
      float a0 = ok ? sy[4 * i + 0][tid + 24] : 0.f;
      float a1 = ok ? sy[4 * i + 1][tid + 24] : 0.f;
      float a2 = ok ? sy[4 * i + 2][tid + 24] : 0.f;
      float a3 = ok ? sy[4 * i + 3][tid + 24] : 0.f;
      w[i] = (unsigned)pk_fp8x4(a0, a1, a2, a3);
    }
    unsigned char* dst = BT8 + (size_t)n * K_DIM + m0;
    *(uint4*)(dst)      = uint4{w[0], w[1], w[2], w[3]};
    *(uint4*)(dst + 16) = uint4{w[4], w[5], w[6], w[7]};
  }
}

// ---------- GEMM: C = W8 @ BT8^T (fp8 MFMA), out = beta * (S + C) ----------
// R16: BK=128 — halve the kstep count at the PROVEN R9 geometry.
// Evidence: R9/R11/R15 sweep shows 2 blocks/CU x 8 waves x 128^2 is the
// only geometry that overlaps (1 block/CU serializes the CU at each
// barrier: R15 = 121 us; 16-wave barriers convoy: R11 = 98 us). Within
// it, per-kstep wall = 3240 cy vs ~620 cy of MFMA issue -> the stall is
// per-kstep FIXED (latency convoy), not bandwidth (ingest 10/15.5 B/cy,
// HBM 14%). BK 64->128 halves barrier count: 32 ksteps x 32 KB staged.
// LDS 2buf x 32 KB = 64 KB -> still exactly 2 blocks/CU (m132's BK=128
// hazard was an occupancy DROP; ours stays 2). 8-slot XOR chunk swizzle
// (key=(m16>>1)&7; write/read keys match for all fragment rows since
// i*16 and wm*64 contribute 0 mod 8 to (row>>1)&7). Ping-pong counted
// vmcnt(4) (4 gl2lds/thread/kstep), wave-uniform LDS bases. k-order
// kt*128+h*32 enumerates k identically to R9's kt*64+h*32 -> bitwise-
// identical accumulation chain.
__global__ __launch_bounds__(512, 4) void k_gemm(const unsigned char* __restrict__ W8,
                                                 const unsigned char* __restrict__ BT8,
                                                 const unsigned short* __restrict__ Sbf,
                                                 const float* __restrict__ b0,
                                                 const float* __restrict__ b1,
                                                 float* __restrict__ out) {
  __shared__ __align__(64) unsigned char lA[2][128 * 128];   // 32 KB
  __shared__ __align__(64) unsigned char lB[2][128 * 128];   // 32 KB
  const int tid  = threadIdx.x;
  const int wave = tid >> 6;          // 0..7
  const int lane = tid & 63;
  const int wm = wave >> 2;           // 0..1 : 64-row slice
  const int wn = wave & 3;            // 0..3 : 32-col slice
  const int m16  = lane & 15;
  const int quad = lane >> 4;

  // XCD-aware bijective swizzle (512%8==0): each XCD gets 64 consecutive
  // tiles = 4 full M-rows -> A-panels L2-local.
  const int fid  = blockIdx.y * gridDim.x + blockIdx.x;   // 0..511
  const int swz  = (fid & 7) * 64 + (fid >> 3);
  const int tileN = (swz & 15) * 128;
  const int tileM = (swz >> 4) * 128;

  // fragment read offsets: 128B rows (K=128 fp8 per kstep).
  // MFMA h (K=32 each, h=0..3): lane reads bytes k = h*32 + quad*8 .. +7
  // chunk c = 2h + (quad>>1) in 0..7; swizzled slot = c ^ ((row>>1)&7);
  // (row>>1)&7 == (m16>>1)&7 for every fragment row (wm*64, i*16 ≡ 0 mod 16).
  const int key  = (m16 >> 1) & 7;
  const int sub  = (quad & 1) * 8;
  const int rowA = (wm * 64 + m16) * 128;
  const int rowB = (wn * 32 + m16) * 128;
  int hOf[4];
#pragma unroll
  for (int h = 0; h < 4; ++h)
    hOf[h] = (((2 * h + (quad >> 1)) ^ key) << 4) + sub;

  // staging: 2 chunks/thread/matrix (16 KB per matrix per kstep).
  // Global addr carries the XOR swizzle; LDS dest stays linear.
  const unsigned char* gA[2];
  const unsigned char* gB[2];
  int ldsBase[2];                          // wave-uniform (HW adds lane*16)
#pragma unroll
  for (int c = 0; c < 2; ++c) {
    int o = c * 8192 + wave * 1024 + lane * 16;   // 0..16383
    int r = o >> 7;                     // row 0..127 (128B rows)
    int s = (o >> 4) & 7;               // LDS chunk slot 0..7
    int q = s ^ ((r >> 1) & 7);         // logical (global) chunk
    gA[c] = W8  + (size_t)(tileM + r) * K_DIM + q * 16;
    gB[c] = BT8 + (size_t)(tileN + r) * K_DIM + q * 16;
    ldsBase[c] = c * 8192 + wave * 1024;
  }

  f32x4 acc[4][2];
#pragma unroll
  for (int i = 0; i < 4; ++i)
#pragma unroll
    for (int j = 0; j < 2; ++j) acc[i][j] = f32x4{0.f, 0.f, 0.f, 0.f};

  // 4 gl2lds (vmcnt events) per tile per thread
  auto stage = [&](int buf, int kt_) {
    const size_t kb_ = (size_t)kt_ * 128;
#pragma unroll
    for (int c = 0; c < 2; ++c) {
      gl2lds16(gA[c] + kb_, &lA[buf][ldsBase[c]]);
      gl2lds16(gB[c] + kb_, &lB[buf][ldsBase[c]]);
    }
  };
  auto compute = [&](int buf) {
#pragma unroll
    for (int h = 0; h < 4; ++h) {
      long long aF[4], bF[2];
#pragma unroll
      for (int i = 0; i < 4; ++i)
        aF[i] = *(const long long*)&lA[buf][rowA + i * 2048 + hOf[h]];
#pragma unroll
      for (int j = 0; j < 2; ++j)
        bF[j] = *(const long long*)&lB[buf][rowB + j * 2048 + hOf[h]];
#pragma unroll
      for (int i = 0; i < 4; ++i)
#pragma unroll
        for (int j = 0; j < 2; ++j)
          acc[i][j] = __builtin_amdgcn_mfma_f32_16x16x32_fp8_fp8(
              aF[i], bF[j], acc[i][j], 0, 0, 0);
    }
  };

  // prologue: tile 0 in flight (4 outstanding per thread)
  stage(0, 0);

#pragma unroll 1
  for (int kt = 0; kt < K_DIM / 128; kt += 2) {
    // even phase: prefetch kt+1 -> buf1 (kt<=30 -> valid), compute buf0
    stage(1, kt + 1);                                  // 8 outstanding
    asm volatile("s_waitcnt vmcnt(4)" ::: "memory");   // tile kt landed
    __builtin_amdgcn_s_barrier();
    asm volatile("" ::: "memory");
    compute(0);
    __builtin_amdgcn_s_barrier();                      // buf0 free for reuse
    asm volatile("" ::: "memory");

    // odd phase: prefetch kt+2 -> buf0, compute buf1
    if (kt + 2 < K_DIM / 128) {
      stage(0, kt + 2);
      asm volatile("s_waitcnt vmcnt(4)" ::: "memory");
    } else {
      asm volatile("s_waitcnt vmcnt(0)" ::: "memory");
    }
    __builtin_amdgcn_s_barrier();
    asm volatile("" ::: "memory");
    compute(1);
    __builtin_amdgcn_s_barrier();
    asm volatile("" ::: "memory");
  }

  // Epilogue: out[gm][gn] = softplus(b0+b1*(gn+25)) * (S[gm][gn] + C)
#pragma unroll
  for (int j = 0; j < 2; ++j) {
    int gn = tileN + wn * 32 + j * 16 + m16;
    if (gn >= N_OUT) continue;
    float tval = (float)(gn + WIN);
#pragma unroll
    for (int i = 0; i < 4; ++i) {
#pragma unroll
      for (int r2 = 0; r2 < 4; ++r2) {
        int gm = tileM + wm * 64 + i * 16 + quad * 4 + r2;
        float x = b0[gm] + b1[gm] * tval;
        float beta = fmaxf(x, 0.f) + log1pf(__expf(-fabsf(x)));
        float sv = bf2f(Sbf[(size_t)gm * N_PAD + gn]);
        out[(size_t)gm * N_OUT + gn] = beta * (sv + acc[i][j][r2]);
      }
    }
  }
}

extern "C" void kernel_launch(void* const* d_in, const int* in_sizes, int n_in,
                              void* d_out, int out_size, void* d_ws, size_t ws_size,
                              hipStream_t stream) {
  const float* ys     = (const float*)d_in[0];
  const float* alphas = (const float*)d_in[1];
  const float* repro  = (const float*)d_in[2];
  const float* b0     = (const float*)d_in[3];
  const float* b1     = (const float*)d_in[4];
  float* out = (float*)d_out;

  char* ws = (char*)d_ws;
  unsigned char*  W8  = (unsigned char*)ws;                                    // 16 MiB
  unsigned char*  BT8 = (unsigned char*)(ws + (size_t)M_DIM * K_DIM);          //  8 MiB
  unsigned short* Sbf = (unsigned short*)(ws + (size_t)M_DIM * K_DIM
                                             + (size_t)N_PAD * K_DIM);         // 16 MiB

  k_wcast<<<(M_DIM * (size_t)K_DIM) / 8 / 256, 256, 0, stream>>>(alphas, W8);
  k_convT<<<dim3(T_DIM / 256, M_DIM / 32), 256, 0, stream>>>(ys, repro, Sbf, BT8);
  k_gemm<<<dim3(N_PAD / 128, M_DIM / 128), 512, 0, stream>>>(W8, BT8, Sbf,
                                                             b0, b1, out);
}